// Round 11
// baseline (1132.201 us; speedup 1.0000x reference)
//
#include <hip/hip_runtime.h>
#include <math.h>

// ---------------------------------------------------------------------------
// JPEG-domain ViT. Round 11: LayerNorm folded into the GEMMs.
//   xn@W = rs*(x@(g*W)) - mu*rs*(sum_k g W) + (sum_k b W)
//  - wconv folds g into the bf16 weights (qkv, w1).
//  - cvec_k precomputes c1[n]=sum_k g W, c2[n]=sum_k b W (+b1 for w1).
//  - Producers (preproc, wo, w2 epilogues) write per-row (sum, sumsq) float2
//    partials per 32-col chunk (unique writer -> deterministic).
//  - Consumers (qkv, w1) reduce the 32 partials in a prologue -> mu*rs, rs,
//    apply LN in the epilogue. ln_k and the xn buffer are gone (-12 dispatches,
//    -75 MB traffic). mm_k loop body = proven round-8 structure, unchanged.
// ---------------------------------------------------------------------------

#define NIMG 16
#define SEQ 192
#define DIMV 1024
#define MROWS (NIMG * SEQ)   // 3072

typedef __attribute__((ext_vector_type(8))) short short8v;
typedef __attribute__((ext_vector_type(4))) float f32x4;
typedef unsigned int uint_t;

__device__ __forceinline__ unsigned short f2bf(float f) {
  union { float f; uint_t u; } x; x.f = f;
  uint_t r = x.u + 0x7fffu + ((x.u >> 16) & 1u);
  return (unsigned short)(r >> 16);
}
__device__ __forceinline__ float bf2f(unsigned short h) {
  union { uint_t u; float f; } y; y.u = ((uint_t)h) << 16;
  return y.f;
}

__device__ __forceinline__ void gload16(const void* g, void* l) {
  __builtin_amdgcn_global_load_lds(
      reinterpret_cast<const __attribute__((address_space(1))) void*>(
          reinterpret_cast<uintptr_t>(g)),
      reinterpret_cast<__attribute__((address_space(3))) void*>(
          reinterpret_cast<uintptr_t>(l)),
      16, 0, 0);
}

__constant__ float DCT8c[8][8] = {
  { 0.35355339f, 0.35355339f, 0.35355339f, 0.35355339f, 0.35355339f, 0.35355339f, 0.35355339f, 0.35355339f},
  { 0.49039264f, 0.41573481f, 0.27778512f, 0.09754516f,-0.09754516f,-0.27778512f,-0.41573481f,-0.49039264f},
  { 0.46193977f, 0.19134172f,-0.19134172f,-0.46193977f,-0.46193977f,-0.19134172f, 0.19134172f, 0.46193977f},
  { 0.41573481f,-0.09754516f,-0.49039264f,-0.27778512f, 0.27778512f, 0.49039264f, 0.09754516f,-0.41573481f},
  { 0.35355339f,-0.35355339f,-0.35355339f, 0.35355339f, 0.35355339f,-0.35355339f,-0.35355339f, 0.35355339f},
  { 0.27778512f,-0.49039264f, 0.09754516f, 0.41573481f,-0.41573481f,-0.09754516f, 0.49039264f,-0.27778512f},
  { 0.19134172f,-0.46193977f, 0.46193977f,-0.19134172f,-0.19134172f, 0.46193977f,-0.46193977f, 0.19134172f},
  { 0.09754516f,-0.27778512f, 0.41573481f,-0.49039264f, 0.49039264f,-0.41573481f, 0.27778512f,-0.09754516f}
};

// ---------------- preprocess: block = (hb, n); writes x bf16 + row partials -
__global__ __launch_bounds__(256) void preproc_k(const float* __restrict__ img,
                                                 unsigned short* __restrict__ x0,
                                                 float2* __restrict__ psum) {
  int hb = blockIdx.x, n = blockIdx.y;
  __shared__ float yuv[3][8][256];
  __shared__ float tmpA[8][264];
  __shared__ float coefc[64][33];
  int t = threadIdx.x;

  #pragma unroll
  for (int u = 0; u < 8; ++u) {
    int idx = u * 256 + t;
    int i = idx >> 8, xx = idx & 255;
    size_t pix = ((size_t)(n * 3) * 256 + hb * 8 + i) * 256 + xx;
    float r = img[pix], g = img[pix + 65536], b = img[pix + 131072];
    yuv[0][i][xx] =  0.299f   * r + 0.587f   * g + 0.114f   * b;
    yuv[1][i][xx] = -0.14713f * r - 0.28886f * g + 0.436f   * b;
    yuv[2][i][xx] =  0.615f   * r - 0.51499f * g - 0.10001f * b;
  }

  for (int c = 0; c < 3; ++c) {
    __syncthreads();
    #pragma unroll
    for (int u = 0; u < 8; ++u) {
      int idx = u * 256 + t;
      int p = idx >> 8, xx = idx & 255;
      float a = 0.f;
      #pragma unroll
      for (int k = 0; k < 8; ++k) a += DCT8c[p][k] * yuv[c][k][xx];
      tmpA[p][xx] = a;
    }
    __syncthreads();
    #pragma unroll
    for (int u = 0; u < 8; ++u) {
      int idx = u * 256 + t;
      int wb = idx >> 6, s = idx & 63;
      int p = s >> 3, qq = s & 7;
      float a = 0.f;
      #pragma unroll
      for (int j = 0; j < 8; ++j) a += tmpA[p][wb * 8 + j] * DCT8c[qq][j];
      bool keep = (c == 0) ? ((p + qq) <= 5 || ((p + qq) == 6 && qq < 4))
                           : ((p + qq) <= 2 || ((p + qq) == 3 && p < 3));
      coefc[s][wb] = keep ? a : 0.f;
    }
    __syncthreads();
    #pragma unroll
    for (int u = 0; u < 8; ++u) {
      int idx = u * 256 + t;
      int s = idx >> 5, wb = idx & 31;
      x0[((size_t)(n * SEQ) + c * 64 + s) * DIMV + hb * 32 + wb] = f2bf(coefc[s][wb]);
    }
    // per-row (sum, sumsq) partials over this block's 32-col chunk (bf16-rounded)
    if (t < 64) {
      float sm = 0.f, sq = 0.f;
      #pragma unroll
      for (int wb = 0; wb < 32; ++wb) {
        float v = bf2f(f2bf(coefc[t][wb]));
        sm += v; sq += v * v;
      }
      psum[(((size_t)(n * SEQ) + c * 64 + t) << 5) + hb] = make_float2(sm, sq);
    }
  }
}

// ---------------- postprocess (coalesced): block = (hb, n), x bf16 ---------
__global__ __launch_bounds__(256) void postproc_k(const unsigned short* __restrict__ x,
                                                  float* __restrict__ out) {
  int hb = blockIdx.x, n = blockIdx.y;
  __shared__ float coefc[64][33];
  __shared__ float tmpA[8][264];
  __shared__ float rec[3][8][256];
  int t = threadIdx.x;

  for (int c = 0; c < 3; ++c) {
    __syncthreads();
    #pragma unroll
    for (int u = 0; u < 8; ++u) {
      int idx = u * 256 + t;
      int s = idx >> 5, wb = idx & 31;
      coefc[s][wb] = bf2f(x[((size_t)(n * SEQ) + c * 64 + s) * DIMV + hb * 32 + wb]);
    }
    __syncthreads();
    #pragma unroll
    for (int u = 0; u < 8; ++u) {
      int idx = u * 256 + t;
      int wb = idx >> 6, iq = idx & 63;
      int i = iq >> 3, qq = iq & 7;
      float a = 0.f;
      #pragma unroll
      for (int p = 0; p < 8; ++p) a += DCT8c[i][p] * coefc[p * 8 + qq][wb];
      tmpA[i][wb * 8 + qq] = a;
    }
    __syncthreads();
    #pragma unroll
    for (int u = 0; u < 8; ++u) {
      int idx = u * 256 + t;
      int i = idx >> 8, xx = idx & 255;
      int wb = xx >> 3, j = xx & 7;
      float a = 0.f;
      #pragma unroll
      for (int qq = 0; qq < 8; ++qq) a += tmpA[i][wb * 8 + qq] * DCT8c[j][qq];
      rec[c][i][xx] = a;
    }
  }
  __syncthreads();
  #pragma unroll
  for (int u = 0; u < 8; ++u) {
    int idx = u * 256 + t;
    int i = idx >> 8, xx = idx & 255;
    float y = rec[0][i][xx], uu = rec[1][i][xx], v = rec[2][i][xx];
    size_t pix = ((size_t)(n * 3) * 256 + hb * 8 + i) * 256 + xx;
    out[pix]          = y + 1.13983f * v;
    out[pix + 65536]  = y - 0.39465f * uu - 0.5806f * v;
    out[pix + 131072] = y + 2.03211f * uu;
  }
}

// ---------------- weight transpose+convert (+optional LN-gamma fold) --------
// w[K][N] fp32 -> wt[N][K] bf16; if g != nullptr, wt[n][k] = bf16(g[k]*w[k][n])
__global__ __launch_bounds__(256) void wconv_k(const float* __restrict__ w,
                                               const float* __restrict__ g,
                                               unsigned short* __restrict__ wt,
                                               int K, int N) {
  int l = blockIdx.z;
  w  += (size_t)l * K * N;
  wt += (size_t)l * K * N;
  __shared__ float s[32][33];
  int t = threadIdx.x;
  int n0 = blockIdx.x << 5, k0 = blockIdx.y << 5;
  int r = t >> 3, c4 = (t & 7) << 2;
  float4 v = *(const float4*)(w + (size_t)(k0 + r) * N + n0 + c4);
  s[r][c4] = v.x; s[r][c4 + 1] = v.y; s[r][c4 + 2] = v.z; s[r][c4 + 3] = v.w;
  __syncthreads();
  float g0 = 1.f, g1 = 1.f, g2 = 1.f, g3 = 1.f;
  if (g) {
    const float* gl = g + (size_t)l * K + k0 + c4;
    g0 = gl[0]; g1 = gl[1]; g2 = gl[2]; g3 = gl[3];
  }
  ushort4 o;
  o.x = f2bf(s[c4 + 0][r] * g0); o.y = f2bf(s[c4 + 1][r] * g1);
  o.z = f2bf(s[c4 + 2][r] * g2); o.w = f2bf(s[c4 + 3][r] * g3);
  *(ushort4*)(wt + (size_t)(n0 + r) * K + k0 + c4) = o;
}

// ---------------- LN-fold column vectors: c1[n]=sum_k g W, c2[n]=sum_k b W --
// (+ optional extra bias bx[n] added to c2, e.g. b1 for the w1 GEMM)
__global__ __launch_bounds__(256) void cvec_k(const float* __restrict__ w,
                                              const float* __restrict__ g,
                                              const float* __restrict__ b,
                                              const float* __restrict__ bx,
                                              float2* __restrict__ out,
                                              int K, int N) {
  int l = blockIdx.y;
  const float* wl = w + (size_t)l * K * N;
  const float* gl = g + (size_t)l * K;
  const float* bl = b + (size_t)l * K;
  int n = blockIdx.x * 256 + threadIdx.x;
  float c1 = 0.f, c2 = 0.f;
  for (int k = 0; k < K; ++k) {
    float wv = wl[(size_t)k * N + n];
    c1 += gl[k] * wv;
    c2 += bl[k] * wv;
  }
  if (bx) c2 += bx[(size_t)l * N + n];
  out[(size_t)l * N + n] = make_float2(c1, c2);
}

// ---------------- bf16 MFMA GEMM: 128x64 tile, 4 waves, BK=64 (round 8) -----
// Loop body unchanged (full-cache-line gload16, counted vmcnt(6), involution
// chunk swizzle, XCD swizzle). New epilogue roles:
//  EPI 0 (qkv): LN-consumer. v = rs*acc - mu*rs*c1[col] + c2[col] -> bf16.
//  EPI 1 (wo/w2): +bias +bf16 residual -> bf16; writes per-row (sum,sumsq)
//                 float2 partial for its 32-col chunk (LN producer).
//  EPI 2 (w1): LN-consumer + exact GELU (c2 already includes b1).
template <int EPI>
__global__ __launch_bounds__(256) void mm_k(const unsigned short* __restrict__ A,
                                            const unsigned short* __restrict__ Bt,
                                            const float* __restrict__ bias,
                                            const unsigned short* res,
                                            const float2* __restrict__ cvec,
                                            const float2* __restrict__ psum_in,
                                            float2* __restrict__ psum_out,
                                            unsigned short* Cout,
                                            int M, int N, int K) {
  __shared__ __align__(16) unsigned short smem[24576];   // 48 KB staging
  __shared__ float rowstats[128][2];                      // mu*rs, rs (EPI!=1)

  int t = threadIdx.x;
  int lane = t & 63, w = t >> 6;          // 4 waves
  int gx = gridDim.x;
  int nwg = gx * gridDim.y;
  int bid = blockIdx.y * gx + blockIdx.x;
  bid = (bid & 7) * (nwg >> 3) + (bid >> 3);      // bijective XCD swizzle
  int m0 = (bid / gx) << 7, n0 = (bid % gx) << 6;
  int wm = (w >> 1) << 6, wn = (w & 1) << 5;

  // LN-consumer prologue: reduce 32 per-row partials -> mu*rs, rs
  if (EPI != 1) {
    if (t < 128) {
      const float2* pr = psum_in + ((size_t)(m0 + t) << 5);
      float sm = 0.f, sq = 0.f;
      #pragma unroll
      for (int i2 = 0; i2 < 32; ++i2) { float2 pv = pr[i2]; sm += pv.x; sq += pv.y; }
      float inv = 1.f / (float)K;
      float mu = sm * inv;
      float var = fmaxf(sq * inv - mu * mu, 0.f);
      float rsv = rsqrtf(var + 1e-5f);
      rowstats[t][0] = mu * rsv;
      rowstats[t][1] = rsv;
    }
    __syncthreads();
  }

  int r_in = lane >> 3, p = lane & 7;
  int sw = (p ^ r_in) << 3;
  const unsigned short* Ag = A + (size_t)(m0 + w * 32 + r_in) * K + sw;
  const unsigned short* Bg = Bt + (size_t)(n0 + w * 16 + r_in) * K + sw;
  char* smb = (char*)smem;
  size_t K8 = (size_t)K * 8;

  f32x4 acc[4][2] = {};

  int m15 = lane & 15, c4 = lane >> 4, s7 = lane & 7;
  int nt = K >> 6;

  #define STAGE(it_, db_) {                                                    \
    size_t k0_ = (size_t)(it_) << 6;                                           \
    gload16(Ag + k0_,          smb + (db_) * 16384 + ((w * 32 +  0) << 7));    \
    gload16(Ag + k0_ + K8,     smb + (db_) * 16384 + ((w * 32 +  8) << 7));    \
    gload16(Ag + k0_ + 2 * K8, smb + (db_) * 16384 + ((w * 32 + 16) << 7));    \
    gload16(Ag + k0_ + 3 * K8, smb + (db_) * 16384 + ((w * 32 + 24) << 7));    \
    gload16(Bg + k0_,          smb + 32768 + (db_) * 8192 + ((w * 16 + 0) << 7)); \
    gload16(Bg + k0_ + K8,     smb + 32768 + (db_) * 8192 + ((w * 16 + 8) << 7)); }

  STAGE(0, 0);
  STAGE(1, 1);

  for (int it = 0; it < nt; ++it) {
    int db = it & 1;
    if (it + 1 < nt) asm volatile("s_waitcnt vmcnt(6)" ::: "memory");
    else             asm volatile("s_waitcnt vmcnt(0)" ::: "memory");
    __builtin_amdgcn_s_barrier();
    const char* Ab = smb + db * 16384;
    const char* Bb = smb + 32768 + db * 8192;
    short8v a[2][4], b[2][2];
    #pragma unroll
    for (int kc = 0; kc < 2; ++kc) {
      int ch = ((kc << 2) + c4);
      #pragma unroll
      for (int mi = 0; mi < 4; ++mi)
        a[kc][mi] = *(const short8v*)(Ab + ((wm + mi * 16 + m15) << 7) + ((ch ^ s7) << 4));
      #pragma unroll
      for (int ni = 0; ni < 2; ++ni)
        b[kc][ni] = *(const short8v*)(Bb + ((wn + ni * 16 + m15) << 7) + ((ch ^ s7) << 4));
    }
    #pragma unroll
    for (int kc = 0; kc < 2; ++kc)
      #pragma unroll
      for (int mi = 0; mi < 4; ++mi)
        #pragma unroll
        for (int ni = 0; ni < 2; ++ni)
          acc[mi][ni] = __builtin_amdgcn_mfma_f32_16x16x32_bf16(a[kc][mi], b[kc][ni], acc[mi][ni], 0, 0, 0);
    __builtin_amdgcn_s_barrier();
    if (it + 2 < nt) STAGE(it + 2, db);
  }
  #undef STAGE

  // epilogue: C/D frag layout col = lane&15, row = (lane>>4)*4 + r  [m89/m91]
  int cn = lane & 15;
  int rbq = (lane >> 4) << 2;
  #pragma unroll
  for (int mi = 0; mi < 4; ++mi) {
    float vq[2][4];
    #pragma unroll
    for (int ni = 0; ni < 2; ++ni) {
      int col = n0 + wn + ni * 16 + cn;
      float2 cv = make_float2(0.f, 0.f);
      float bv = 0.f;
      if (EPI != 1) cv = cvec[col];
      else          bv = bias[col];
      #pragma unroll
      for (int r = 0; r < 4; ++r) {
        int row = m0 + wm + mi * 16 + rbq + r;
        float v = acc[mi][ni][r];
        if (EPI == 1) {
          v += bv + bf2f(res[(size_t)row * N + col]);
          unsigned short hv = f2bf(v);
          Cout[(size_t)row * N + col] = hv;
          vq[ni][r] = bf2f(hv);
        } else {
          int lr = wm + mi * 16 + rbq + r;
          float v2 = rowstats[lr][1] * v - rowstats[lr][0] * cv.x + cv.y;
          if (EPI == 2) v2 = 0.5f * v2 * (1.f + erff(v2 * 0.70710678f));
          Cout[(size_t)row * N + col] = f2bf(v2);
        }
      }
    }
    if (EPI == 1) {
      #pragma unroll
      for (int r = 0; r < 4; ++r) {
        float sm = vq[0][r] + vq[1][r];
        float sq = vq[0][r] * vq[0][r] + vq[1][r] * vq[1][r];
        #pragma unroll
        for (int msk = 1; msk <= 8; msk <<= 1) {
          sm += __shfl_xor(sm, msk, 64);
          sq += __shfl_xor(sq, msk, 64);
        }
        if ((lane & 15) == 0) {
          int row = m0 + wm + mi * 16 + rbq + r;
          psum_out[((size_t)row << 5) + ((n0 + wn) >> 5)] = make_float2(sm, sq);
        }
      }
    }
  }
}

// ---------------- MFMA attention (round 3, unchanged) -----------------------
__global__ __launch_bounds__(256) void attn_k(const unsigned short* __restrict__ qkv,
                                              unsigned short* __restrict__ o) {
  int qt = blockIdx.x, h = blockIdx.y, n = blockIdx.z;
  int t = threadIdx.x, lane = t & 63, w = t >> 6;
  __shared__ __align__(16) unsigned short Ks[192 * 64];
  __shared__ __align__(16) unsigned short Vt[64 * 192];
  __shared__ __align__(16) unsigned short Ps[4][16 * 192];
  const unsigned short* base = qkv + (size_t)n * SEQ * 1536;

  #pragma unroll
  for (int i = 0; i < 6; ++i) {
    int idx = i * 256 + t;
    int row = idx >> 3, c8 = (idx & 7) << 3;
    short8v kv = *(const short8v*)(base + (size_t)row * 1536 + 512 + h * 64 + c8);
    int kb = (row * 128 + c8 * 2) ^ ((row & 7) << 4);
    *(short8v*)((char*)Ks + kb) = kv;
  }
  #pragma unroll
  for (int i = 0; i < 6; ++i) {
    int idx = i * 256 + t;
    int j = (idx & 63) + ((idx >> 9) << 6);
    int d0 = ((idx >> 6) & 7) << 3;
    short8v vv = *(const short8v*)(base + (size_t)j * 1536 + 1024 + h * 64 + d0);
    #pragma unroll
    for (int e = 0; e < 8; ++e) {
      int d = d0 + e;
      int vb = (d * 384 + j * 2) ^ ((d & 7) << 4);
      *(unsigned short*)((char*)Vt + vb) = (unsigned short)vv[e];
    }
  }
  int q0 = qt * 64 + w * 16;
  const unsigned short* qp = base + (size_t)(q0 + (lane & 15)) * 1536 + h * 64 + ((lane >> 4) << 3);
  short8v aq0 = *(const short8v*)(qp);
  short8v aq1 = *(const short8v*)(qp + 32);
  __syncthreads();

  f32x4 sa[12];
  #pragma unroll
  for (int ni = 0; ni < 12; ++ni) sa[ni] = (f32x4){0.f, 0.f, 0.f, 0.f};
  #pragma unroll
  for (int ks = 0; ks < 2; ++ks) {
    int kk = (ks << 5) + ((lane >> 4) << 3);
    short8v aq = ks ? aq1 : aq0;
    #pragma unroll
    for (int ni = 0; ni < 12; ++ni) {
      int krow = ni * 16 + (lane & 15);
      int kb = (krow * 128 + kk * 2) ^ ((krow & 7) << 4);
      short8v bk = *(const short8v*)((char*)Ks + kb);
      sa[ni] = __builtin_amdgcn_mfma_f32_16x16x32_bf16(aq, bk, sa[ni], 0, 0, 0);
    }
  }

  unsigned short* Pw = Ps[w];
  float l4[4];
  #pragma unroll
  for (int r = 0; r < 4; ++r) {
    float mx = sa[0][r];
    #pragma unroll
    for (int ni = 1; ni < 12; ++ni) mx = fmaxf(mx, sa[ni][r]);
    mx = fmaxf(mx, __shfl_xor(mx, 1, 64));
    mx = fmaxf(mx, __shfl_xor(mx, 2, 64));
    mx = fmaxf(mx, __shfl_xor(mx, 4, 64));
    mx = fmaxf(mx, __shfl_xor(mx, 8, 64));
    int prow = ((lane >> 4) << 2) + r;
    float sum = 0.f;
    #pragma unroll
    for (int ni = 0; ni < 12; ++ni) {
      float p = __expf((sa[ni][r] - mx) * 0.125f);
      sum += p;
      int col = ni * 16 + (lane & 15);
      int pb = (prow * 384 + col * 2) ^ ((prow & 7) << 4);
      *(unsigned short*)((char*)Pw + pb) = f2bf(p);
    }
    sum += __shfl_xor(sum, 1, 64);
    sum += __shfl_xor(sum, 2, 64);
    sum += __shfl_xor(sum, 4, 64);
    sum += __shfl_xor(sum, 8, 64);
    l4[r] = sum;
  }

  f32x4 oa[4];
  #pragma unroll
  for (int ni = 0; ni < 4; ++ni) oa[ni] = (f32x4){0.f, 0.f, 0.f, 0.f};
  #pragma unroll
  for (int ks = 0; ks < 6; ++ks) {
    int kk = (ks << 5) + ((lane >> 4) << 3);
    int m = lane & 15;
    int pb = (m * 384 + kk * 2) ^ ((m & 7) << 4);
    short8v pa = *(const short8v*)((char*)Pw + pb);
    #pragma unroll
    for (int ni = 0; ni < 4; ++ni) {
      int vrow = ni * 16 + (lane & 15);
      int vb = (vrow * 384 + kk * 2) ^ ((vrow & 7) << 4);
      short8v vbf = *(const short8v*)((char*)Vt + vb);
      oa[ni] = __builtin_amdgcn_mfma_f32_16x16x32_bf16(pa, vbf, oa[ni], 0, 0, 0);
    }
  }

  int rbq = (lane >> 4) << 2;
  #pragma unroll
  for (int r = 0; r < 4; ++r) {
    float inv = 1.f / l4[r];
    unsigned short* dst = o + (size_t)(n * SEQ + q0 + rbq + r) * 512 + h * 64 + (lane & 15);
    #pragma unroll
    for (int ni = 0; ni < 4; ++ni)
      dst[ni * 16] = f2bf(oa[ni][r] * inv);
  }
}

// ---------------------------------------------------------------------------
extern "C" void kernel_launch(void* const* d_in, const int* in_sizes, int n_in,
                              void* d_out, int out_size, void* d_ws, size_t ws_size,
                              hipStream_t stream) {
  const float* img   = (const float*)d_in[0];
  const float* ln1_g = (const float*)d_in[1];
  const float* ln1_b = (const float*)d_in[2];
  const float* wqkv  = (const float*)d_in[3];
  const float* wo    = (const float*)d_in[4];
  const float* bo    = (const float*)d_in[5];
  const float* ln2_g = (const float*)d_in[6];
  const float* ln2_b = (const float*)d_in[7];
  const float* w1    = (const float*)d_in[8];
  const float* b1    = (const float*)d_in[9];
  const float* w2    = (const float*)d_in[10];
  const float* b2    = (const float*)d_in[11];
  float* out = (float*)d_out;

  char* ws = (char*)d_ws;
  unsigned short* x    = (unsigned short*)ws;               //  6,291,456 (bf16)
  unsigned short* big  = (unsigned short*)(ws + 6291456);   // 12,582,912
  unsigned short* ob   = (unsigned short*)(ws + 18874368);  //  3,145,728
  float2*         psum = (float2*)(ws + 22020096);          //    786,432
  float2*         cvq  = (float2*)(ws + 22806528);          //     73,728 (6x1536)
  float2*         cvw  = (float2*)(ws + 22880256);          //     98,304 (6x2048)
  unsigned short* wtb  = (unsigned short*)(ws + 22978560);  // weight area

  // all-layer weight area needs 75,497,472 B -> total 98,476,032
  bool big_ws = (ws_size >= 98476032ull);
  size_t per_qkv = (size_t)1024 * 1536, per_o = (size_t)512 * 1024;
  size_t per_1   = (size_t)1024 * 2048, per_2 = (size_t)2048 * 1024;
  unsigned short *wt_qkv, *wt_o, *wt_1, *wt_2;
  if (big_ws) {
    wt_qkv = wtb;
    wt_o   = wt_qkv + 6 * per_qkv;
    wt_1   = wt_o   + 6 * per_o;
    wt_2   = wt_1   + 6 * per_1;
    wconv_k<<<dim3(1536 / 32, 1024 / 32, 6), 256, 0, stream>>>(wqkv, ln1_g, wt_qkv, 1024, 1536);
    wconv_k<<<dim3(1024 / 32,  512 / 32, 6), 256, 0, stream>>>(wo,   nullptr, wt_o,  512, 1024);
    wconv_k<<<dim3(2048 / 32, 1024 / 32, 6), 256, 0, stream>>>(w1,   ln2_g, wt_1,   1024, 2048);
    wconv_k<<<dim3(1024 / 32, 2048 / 32, 6), 256, 0, stream>>>(w2,   nullptr, wt_2, 2048, 1024);
    cvec_k<<<dim3(1536 / 256, 6), 256, 0, stream>>>(wqkv, ln1_g, ln1_b, nullptr, cvq, 1024, 1536);
    cvec_k<<<dim3(2048 / 256, 6), 256, 0, stream>>>(w1,   ln2_g, ln2_b, b1,      cvw, 1024, 2048);
  } else {
    wt_qkv = wtb;
    wt_o   = wt_qkv + per_qkv;
    wt_1   = wt_o + per_o;
    wt_2   = wt_1 + per_1;
  }

  preproc_k<<<dim3(32, 16), 256, 0, stream>>>(img, x, psum);

  for (int l = 0; l < 6; ++l) {
    unsigned short *wq_l, *wo_l, *w1_l, *w2_l;
    const float2 *cvq_l, *cvw_l;
    if (big_ws) {
      wq_l = wt_qkv + l * per_qkv; wo_l = wt_o + l * per_o;
      w1_l = wt_1 + l * per_1;     w2_l = wt_2 + l * per_2;
      cvq_l = cvq + l * 1536;      cvw_l = cvw + l * 2048;
    } else {
      wconv_k<<<dim3(1536 / 32, 1024 / 32), 256, 0, stream>>>(wqkv + l * per_qkv, ln1_g + l * 1024, wt_qkv, 1024, 1536);
      wconv_k<<<dim3(1024 / 32,  512 / 32), 256, 0, stream>>>(wo   + l * per_o,   nullptr,          wt_o,    512, 1024);
      wconv_k<<<dim3(2048 / 32, 1024 / 32), 256, 0, stream>>>(w1   + l * per_1,   ln2_g + l * 1024, wt_1,   1024, 2048);
      wconv_k<<<dim3(1024 / 32, 2048 / 32), 256, 0, stream>>>(w2   + l * per_2,   nullptr,          wt_2,   2048, 1024);
      cvec_k<<<dim3(1536 / 256, 1), 256, 0, stream>>>(wqkv + l * per_qkv, ln1_g + l * 1024, ln1_b + l * 1024, nullptr,       cvq, 1024, 1536);
      cvec_k<<<dim3(2048 / 256, 1), 256, 0, stream>>>(w1   + l * per_1,   ln2_g + l * 1024, ln2_b + l * 1024, b1 + l * 2048, cvw, 1024, 2048);
      wq_l = wt_qkv; wo_l = wt_o; w1_l = wt_1; w2_l = wt_2;
      cvq_l = cvq; cvw_l = cvw;
    }

    // qkv: LN1-folded consumer
    mm_k<0><<<dim3(1536 / 64, 24), 256, 0, stream>>>(
        x, wq_l, nullptr, nullptr, cvq_l, psum, nullptr, big, MROWS, 1536, 1024);
    attn_k<<<dim3(3, 8, 16), 256, 0, stream>>>(big, ob);
    // wo: residual writer + LN2 stats producer
    mm_k<1><<<dim3(1024 / 64, 24), 256, 0, stream>>>(
        ob, wo_l, bo + l * 1024, x, nullptr, nullptr, psum, x, MROWS, 1024, 512);
    // w1: LN2-folded consumer + GELU
    mm_k<2><<<dim3(2048 / 64, 24), 256, 0, stream>>>(
        x, w1_l, nullptr, nullptr, cvw_l, psum, nullptr, big, MROWS, 2048, 1024);
    // w2: residual writer + next-layer LN1 stats producer
    mm_k<1><<<dim3(1024 / 64, 24), 256, 0, stream>>>(
        big, w2_l, b2 + l * 1024, x, nullptr, nullptr, psum, x, MROWS, 1024, 2048);
  }

  postproc_k<<<dim3(32, 16), 256, 0, stream>>>(x, out);
}

// Round 12
// 803.874 us; speedup vs baseline: 1.4084x; 1.4084x over previous
//
#include <hip/hip_runtime.h>
#include <math.h>

// ---------------------------------------------------------------------------
// JPEG-domain ViT. Round 12: round-11 LN-fold kept (verified correct), but
// cvec_k (243 us x12, latency-bound: 6-8 blocks, serial K loop) is replaced:
//  - wconv_k now emits per-32-row-chunk column partials (c1=sum g*W,
//    c2=sum b*W) from the W tile it already stages in LDS.
//  - cvred_k (N/256 blocks) reduces the 32 chunk partials + adds b1.
// Dead big_ws branch removed (ws_size < 98.5 MB -> it never ran).
// ---------------------------------------------------------------------------

#define NIMG 16
#define SEQ 192
#define DIMV 1024
#define MROWS (NIMG * SEQ)   // 3072

typedef __attribute__((ext_vector_type(8))) short short8v;
typedef __attribute__((ext_vector_type(4))) float f32x4;
typedef unsigned int uint_t;

__device__ __forceinline__ unsigned short f2bf(float f) {
  union { float f; uint_t u; } x; x.f = f;
  uint_t r = x.u + 0x7fffu + ((x.u >> 16) & 1u);
  return (unsigned short)(r >> 16);
}
__device__ __forceinline__ float bf2f(unsigned short h) {
  union { uint_t u; float f; } y; y.u = ((uint_t)h) << 16;
  return y.f;
}

__device__ __forceinline__ void gload16(const void* g, void* l) {
  __builtin_amdgcn_global_load_lds(
      reinterpret_cast<const __attribute__((address_space(1))) void*>(
          reinterpret_cast<uintptr_t>(g)),
      reinterpret_cast<__attribute__((address_space(3))) void*>(
          reinterpret_cast<uintptr_t>(l)),
      16, 0, 0);
}

__constant__ float DCT8c[8][8] = {
  { 0.35355339f, 0.35355339f, 0.35355339f, 0.35355339f, 0.35355339f, 0.35355339f, 0.35355339f, 0.35355339f},
  { 0.49039264f, 0.41573481f, 0.27778512f, 0.09754516f,-0.09754516f,-0.27778512f,-0.41573481f,-0.49039264f},
  { 0.46193977f, 0.19134172f,-0.19134172f,-0.46193977f,-0.46193977f,-0.19134172f, 0.19134172f, 0.46193977f},
  { 0.41573481f,-0.09754516f,-0.49039264f,-0.27778512f, 0.27778512f, 0.49039264f, 0.09754516f,-0.41573481f},
  { 0.35355339f,-0.35355339f,-0.35355339f, 0.35355339f, 0.35355339f,-0.35355339f,-0.35355339f, 0.35355339f},
  { 0.27778512f,-0.49039264f, 0.09754516f, 0.41573481f,-0.41573481f,-0.09754516f, 0.49039264f,-0.27778512f},
  { 0.19134172f,-0.46193977f, 0.46193977f,-0.19134172f,-0.19134172f, 0.46193977f,-0.46193977f, 0.19134172f},
  { 0.09754516f,-0.27778512f, 0.41573481f,-0.49039264f, 0.49039264f,-0.41573481f, 0.27778512f,-0.09754516f}
};

// ---------------- preprocess: block = (hb, n); writes x bf16 + row partials -
__global__ __launch_bounds__(256) void preproc_k(const float* __restrict__ img,
                                                 unsigned short* __restrict__ x0,
                                                 float2* __restrict__ psum) {
  int hb = blockIdx.x, n = blockIdx.y;
  __shared__ float yuv[3][8][256];
  __shared__ float tmpA[8][264];
  __shared__ float coefc[64][33];
  int t = threadIdx.x;

  #pragma unroll
  for (int u = 0; u < 8; ++u) {
    int idx = u * 256 + t;
    int i = idx >> 8, xx = idx & 255;
    size_t pix = ((size_t)(n * 3) * 256 + hb * 8 + i) * 256 + xx;
    float r = img[pix], g = img[pix + 65536], b = img[pix + 131072];
    yuv[0][i][xx] =  0.299f   * r + 0.587f   * g + 0.114f   * b;
    yuv[1][i][xx] = -0.14713f * r - 0.28886f * g + 0.436f   * b;
    yuv[2][i][xx] =  0.615f   * r - 0.51499f * g - 0.10001f * b;
  }

  for (int c = 0; c < 3; ++c) {
    __syncthreads();
    #pragma unroll
    for (int u = 0; u < 8; ++u) {
      int idx = u * 256 + t;
      int p = idx >> 8, xx = idx & 255;
      float a = 0.f;
      #pragma unroll
      for (int k = 0; k < 8; ++k) a += DCT8c[p][k] * yuv[c][k][xx];
      tmpA[p][xx] = a;
    }
    __syncthreads();
    #pragma unroll
    for (int u = 0; u < 8; ++u) {
      int idx = u * 256 + t;
      int wb = idx >> 6, s = idx & 63;
      int p = s >> 3, qq = s & 7;
      float a = 0.f;
      #pragma unroll
      for (int j = 0; j < 8; ++j) a += tmpA[p][wb * 8 + j] * DCT8c[qq][j];
      bool keep = (c == 0) ? ((p + qq) <= 5 || ((p + qq) == 6 && qq < 4))
                           : ((p + qq) <= 2 || ((p + qq) == 3 && p < 3));
      coefc[s][wb] = keep ? a : 0.f;
    }
    __syncthreads();
    #pragma unroll
    for (int u = 0; u < 8; ++u) {
      int idx = u * 256 + t;
      int s = idx >> 5, wb = idx & 31;
      x0[((size_t)(n * SEQ) + c * 64 + s) * DIMV + hb * 32 + wb] = f2bf(coefc[s][wb]);
    }
    if (t < 64) {
      float sm = 0.f, sq = 0.f;
      #pragma unroll
      for (int wb = 0; wb < 32; ++wb) {
        float v = bf2f(f2bf(coefc[t][wb]));
        sm += v; sq += v * v;
      }
      psum[(((size_t)(n * SEQ) + c * 64 + t) << 5) + hb] = make_float2(sm, sq);
    }
  }
}

// ---------------- postprocess (coalesced): block = (hb, n), x bf16 ---------
__global__ __launch_bounds__(256) void postproc_k(const unsigned short* __restrict__ x,
                                                  float* __restrict__ out) {
  int hb = blockIdx.x, n = blockIdx.y;
  __shared__ float coefc[64][33];
  __shared__ float tmpA[8][264];
  __shared__ float rec[3][8][256];
  int t = threadIdx.x;

  for (int c = 0; c < 3; ++c) {
    __syncthreads();
    #pragma unroll
    for (int u = 0; u < 8; ++u) {
      int idx = u * 256 + t;
      int s = idx >> 5, wb = idx & 31;
      coefc[s][wb] = bf2f(x[((size_t)(n * SEQ) + c * 64 + s) * DIMV + hb * 32 + wb]);
    }
    __syncthreads();
    #pragma unroll
    for (int u = 0; u < 8; ++u) {
      int idx = u * 256 + t;
      int wb = idx >> 6, iq = idx & 63;
      int i = iq >> 3, qq = iq & 7;
      float a = 0.f;
      #pragma unroll
      for (int p = 0; p < 8; ++p) a += DCT8c[i][p] * coefc[p * 8 + qq][wb];
      tmpA[i][wb * 8 + qq] = a;
    }
    __syncthreads();
    #pragma unroll
    for (int u = 0; u < 8; ++u) {
      int idx = u * 256 + t;
      int i = idx >> 8, xx = idx & 255;
      int wb = xx >> 3, j = xx & 7;
      float a = 0.f;
      #pragma unroll
      for (int qq = 0; qq < 8; ++qq) a += tmpA[i][wb * 8 + qq] * DCT8c[j][qq];
      rec[c][i][xx] = a;
    }
  }
  __syncthreads();
  #pragma unroll
  for (int u = 0; u < 8; ++u) {
    int idx = u * 256 + t;
    int i = idx >> 8, xx = idx & 255;
    float y = rec[0][i][xx], uu = rec[1][i][xx], v = rec[2][i][xx];
    size_t pix = ((size_t)(n * 3) * 256 + hb * 8 + i) * 256 + xx;
    out[pix]          = y + 1.13983f * v;
    out[pix + 65536]  = y - 0.39465f * uu - 0.5806f * v;
    out[pix + 131072] = y + 2.03211f * uu;
  }
}

// ---------------- weight transpose+convert (+gamma fold, +column partials) --
// w[K][N] fp32 -> wt[N][K] bf16 (wt[n][k] = g[k]*w[k][n] if g).
// If pcv: also writes per-32-row-chunk column partials
//   pcv[(k0/32)*N + n] = (sum_r g w, sum_r b w) over r in [k0, k0+32).
__global__ __launch_bounds__(256) void wconv_k(const float* __restrict__ w,
                                               const float* __restrict__ g,
                                               const float* __restrict__ b,
                                               unsigned short* __restrict__ wt,
                                               float2* __restrict__ pcv,
                                               int K, int N) {
  __shared__ float s[32][33];
  int t = threadIdx.x;
  int n0 = blockIdx.x << 5, k0 = blockIdx.y << 5;
  int r = t >> 3, c4 = (t & 7) << 2;
  float4 v = *(const float4*)(w + (size_t)(k0 + r) * N + n0 + c4);
  s[r][c4] = v.x; s[r][c4 + 1] = v.y; s[r][c4 + 2] = v.z; s[r][c4 + 3] = v.w;
  __syncthreads();
  float g0 = 1.f, g1 = 1.f, g2 = 1.f, g3 = 1.f;
  if (g) {
    g0 = g[k0 + c4]; g1 = g[k0 + c4 + 1]; g2 = g[k0 + c4 + 2]; g3 = g[k0 + c4 + 3];
  }
  ushort4 o;
  o.x = f2bf(s[c4 + 0][r] * g0); o.y = f2bf(s[c4 + 1][r] * g1);
  o.z = f2bf(s[c4 + 2][r] * g2); o.w = f2bf(s[c4 + 3][r] * g3);
  *(ushort4*)(wt + (size_t)(n0 + r) * K + k0 + c4) = o;
  if (pcv && t < 32) {
    float c1 = 0.f, c2 = 0.f;
    #pragma unroll
    for (int rr = 0; rr < 32; ++rr) {
      float wv = s[rr][t];
      c1 += g[k0 + rr] * wv;
      c2 += b[k0 + rr] * wv;
    }
    pcv[(size_t)(k0 >> 5) * N + n0 + t] = make_float2(c1, c2);
  }
}

// ---------------- reduce chunk partials -> cvec[n] (+extra bias bx) ---------
__global__ __launch_bounds__(256) void cvred_k(const float2* __restrict__ pcv,
                                               const float* __restrict__ bx,
                                               float2* __restrict__ outv,
                                               int KC, int N) {
  int n = blockIdx.x * 256 + threadIdx.x;
  float c1 = 0.f, c2 = 0.f;
  for (int c = 0; c < KC; ++c) {
    float2 p = pcv[(size_t)c * N + n];
    c1 += p.x; c2 += p.y;
  }
  if (bx) c2 += bx[n];
  outv[n] = make_float2(c1, c2);
}

// ---------------- bf16 MFMA GEMM: 128x64 tile, 4 waves, BK=64 (round 8) -----
//  EPI 0 (qkv): LN-consumer. v = rs*acc - mu*rs*c1[col] + c2[col] -> bf16.
//  EPI 1 (wo/w2): +bias +bf16 residual -> bf16; writes per-row (sum,sumsq)
//                 float2 partial for its 32-col chunk (LN producer).
//  EPI 2 (w1): LN-consumer + exact GELU (c2 already includes b1).
template <int EPI>
__global__ __launch_bounds__(256) void mm_k(const unsigned short* __restrict__ A,
                                            const unsigned short* __restrict__ Bt,
                                            const float* __restrict__ bias,
                                            const unsigned short* res,
                                            const float2* __restrict__ cvec,
                                            const float2* __restrict__ psum_in,
                                            float2* __restrict__ psum_out,
                                            unsigned short* Cout,
                                            int M, int N, int K) {
  __shared__ __align__(16) unsigned short smem[24576];   // 48 KB staging
  __shared__ float rowstats[128][2];                      // mu*rs, rs (EPI!=1)

  int t = threadIdx.x;
  int lane = t & 63, w = t >> 6;          // 4 waves
  int gx = gridDim.x;
  int nwg = gx * gridDim.y;
  int bid = blockIdx.y * gx + blockIdx.x;
  bid = (bid & 7) * (nwg >> 3) + (bid >> 3);      // bijective XCD swizzle
  int m0 = (bid / gx) << 7, n0 = (bid % gx) << 6;
  int wm = (w >> 1) << 6, wn = (w & 1) << 5;

  if (EPI != 1) {
    if (t < 128) {
      const float2* pr = psum_in + ((size_t)(m0 + t) << 5);
      float sm = 0.f, sq = 0.f;
      #pragma unroll
      for (int i2 = 0; i2 < 32; ++i2) { float2 pv = pr[i2]; sm += pv.x; sq += pv.y; }
      float inv = 1.f / (float)K;
      float mu = sm * inv;
      float var = fmaxf(sq * inv - mu * mu, 0.f);
      float rsv = rsqrtf(var + 1e-5f);
      rowstats[t][0] = mu * rsv;
      rowstats[t][1] = rsv;
    }
    __syncthreads();
  }

  int r_in = lane >> 3, p = lane & 7;
  int sw = (p ^ r_in) << 3;
  const unsigned short* Ag = A + (size_t)(m0 + w * 32 + r_in) * K + sw;
  const unsigned short* Bg = Bt + (size_t)(n0 + w * 16 + r_in) * K + sw;
  char* smb = (char*)smem;
  size_t K8 = (size_t)K * 8;

  f32x4 acc[4][2] = {};

  int m15 = lane & 15, c4 = lane >> 4, s7 = lane & 7;
  int nt = K >> 6;

  #define STAGE(it_, db_) {                                                    \
    size_t k0_ = (size_t)(it_) << 6;                                           \
    gload16(Ag + k0_,          smb + (db_) * 16384 + ((w * 32 +  0) << 7));    \
    gload16(Ag + k0_ + K8,     smb + (db_) * 16384 + ((w * 32 +  8) << 7));    \
    gload16(Ag + k0_ + 2 * K8, smb + (db_) * 16384 + ((w * 32 + 16) << 7));    \
    gload16(Ag + k0_ + 3 * K8, smb + (db_) * 16384 + ((w * 32 + 24) << 7));    \
    gload16(Bg + k0_,          smb + 32768 + (db_) * 8192 + ((w * 16 + 0) << 7)); \
    gload16(Bg + k0_ + K8,     smb + 32768 + (db_) * 8192 + ((w * 16 + 8) << 7)); }

  STAGE(0, 0);
  STAGE(1, 1);

  for (int it = 0; it < nt; ++it) {
    int db = it & 1;
    if (it + 1 < nt) asm volatile("s_waitcnt vmcnt(6)" ::: "memory");
    else             asm volatile("s_waitcnt vmcnt(0)" ::: "memory");
    __builtin_amdgcn_s_barrier();
    const char* Ab = smb + db * 16384;
    const char* Bb = smb + 32768 + db * 8192;
    short8v a[2][4], b[2][2];
    #pragma unroll
    for (int kc = 0; kc < 2; ++kc) {
      int ch = ((kc << 2) + c4);
      #pragma unroll
      for (int mi = 0; mi < 4; ++mi)
        a[kc][mi] = *(const short8v*)(Ab + ((wm + mi * 16 + m15) << 7) + ((ch ^ s7) << 4));
      #pragma unroll
      for (int ni = 0; ni < 2; ++ni)
        b[kc][ni] = *(const short8v*)(Bb + ((wn + ni * 16 + m15) << 7) + ((ch ^ s7) << 4));
    }
    #pragma unroll
    for (int kc = 0; kc < 2; ++kc)
      #pragma unroll
      for (int mi = 0; mi < 4; ++mi)
        #pragma unroll
        for (int ni = 0; ni < 2; ++ni)
          acc[mi][ni] = __builtin_amdgcn_mfma_f32_16x16x32_bf16(a[kc][mi], b[kc][ni], acc[mi][ni], 0, 0, 0);
    __builtin_amdgcn_s_barrier();
    if (it + 2 < nt) STAGE(it + 2, db);
  }
  #undef STAGE

  // epilogue: C/D frag layout col = lane&15, row = (lane>>4)*4 + r  [m89/m91]
  int cn = lane & 15;
  int rbq = (lane >> 4) << 2;
  #pragma unroll
  for (int mi = 0; mi < 4; ++mi) {
    float vq[2][4];
    #pragma unroll
    for (int ni = 0; ni < 2; ++ni) {
      int col = n0 + wn + ni * 16 + cn;
      float2 cv = make_float2(0.f, 0.f);
      float bv = 0.f;
      if (EPI != 1) cv = cvec[col];
      else          bv = bias[col];
      #pragma unroll
      for (int r = 0; r < 4; ++r) {
        int row = m0 + wm + mi * 16 + rbq + r;
        float v = acc[mi][ni][r];
        if (EPI == 1) {
          v += bv + bf2f(res[(size_t)row * N + col]);
          unsigned short hv = f2bf(v);
          Cout[(size_t)row * N + col] = hv;
          vq[ni][r] = bf2f(hv);
        } else {
          int lr = wm + mi * 16 + rbq + r;
          float v2 = rowstats[lr][1] * v - rowstats[lr][0] * cv.x + cv.y;
          if (EPI == 2) v2 = 0.5f * v2 * (1.f + erff(v2 * 0.70710678f));
          Cout[(size_t)row * N + col] = f2bf(v2);
        }
      }
    }
    if (EPI == 1) {
      #pragma unroll
      for (int r = 0; r < 4; ++r) {
        float sm = vq[0][r] + vq[1][r];
        float sq = vq[0][r] * vq[0][r] + vq[1][r] * vq[1][r];
        #pragma unroll
        for (int msk = 1; msk <= 8; msk <<= 1) {
          sm += __shfl_xor(sm, msk, 64);
          sq += __shfl_xor(sq, msk, 64);
        }
        if ((lane & 15) == 0) {
          int row = m0 + wm + mi * 16 + rbq + r;
          psum_out[((size_t)row << 5) + ((n0 + wn) >> 5)] = make_float2(sm, sq);
        }
      }
    }
  }
}

// ---------------- MFMA attention (round 3, unchanged) -----------------------
__global__ __launch_bounds__(256) void attn_k(const unsigned short* __restrict__ qkv,
                                              unsigned short* __restrict__ o) {
  int qt = blockIdx.x, h = blockIdx.y, n = blockIdx.z;
  int t = threadIdx.x, lane = t & 63, w = t >> 6;
  __shared__ __align__(16) unsigned short Ks[192 * 64];
  __shared__ __align__(16) unsigned short Vt[64 * 192];
  __shared__ __align__(16) unsigned short Ps[4][16 * 192];
  const unsigned short* base = qkv + (size_t)n * SEQ * 1536;

  #pragma unroll
  for (int i = 0; i < 6; ++i) {
    int idx = i * 256 + t;
    int row = idx >> 3, c8 = (idx & 7) << 3;
    short8v kv = *(const short8v*)(base + (size_t)row * 1536 + 512 + h * 64 + c8);
    int kb = (row * 128 + c8 * 2) ^ ((row & 7) << 4);
    *(short8v*)((char*)Ks + kb) = kv;
  }
  #pragma unroll
  for (int i = 0; i < 6; ++i) {
    int idx = i * 256 + t;
    int j = (idx & 63) + ((idx >> 9) << 6);
    int d0 = ((idx >> 6) & 7) << 3;
    short8v vv = *(const short8v*)(base + (size_t)j * 1536 + 1024 + h * 64 + d0);
    #pragma unroll
    for (int e = 0; e < 8; ++e) {
      int d = d0 + e;
      int vb = (d * 384 + j * 2) ^ ((d & 7) << 4);
      *(unsigned short*)((char*)Vt + vb) = (unsigned short)vv[e];
    }
  }
  int q0 = qt * 64 + w * 16;
  const unsigned short* qp = base + (size_t)(q0 + (lane & 15)) * 1536 + h * 64 + ((lane >> 4) << 3);
  short8v aq0 = *(const short8v*)(qp);
  short8v aq1 = *(const short8v*)(qp + 32);
  __syncthreads();

  f32x4 sa[12];
  #pragma unroll
  for (int ni = 0; ni < 12; ++ni) sa[ni] = (f32x4){0.f, 0.f, 0.f, 0.f};
  #pragma unroll
  for (int ks = 0; ks < 2; ++ks) {
    int kk = (ks << 5) + ((lane >> 4) << 3);
    short8v aq = ks ? aq1 : aq0;
    #pragma unroll
    for (int ni = 0; ni < 12; ++ni) {
      int krow = ni * 16 + (lane & 15);
      int kb = (krow * 128 + kk * 2) ^ ((krow & 7) << 4);
      short8v bk = *(const short8v*)((char*)Ks + kb);
      sa[ni] = __builtin_amdgcn_mfma_f32_16x16x32_bf16(aq, bk, sa[ni], 0, 0, 0);
    }
  }

  unsigned short* Pw = Ps[w];
  float l4[4];
  #pragma unroll
  for (int r = 0; r < 4; ++r) {
    float mx = sa[0][r];
    #pragma unroll
    for (int ni = 1; ni < 12; ++ni) mx = fmaxf(mx, sa[ni][r]);
    mx = fmaxf(mx, __shfl_xor(mx, 1, 64));
    mx = fmaxf(mx, __shfl_xor(mx, 2, 64));
    mx = fmaxf(mx, __shfl_xor(mx, 4, 64));
    mx = fmaxf(mx, __shfl_xor(mx, 8, 64));
    int prow = ((lane >> 4) << 2) + r;
    float sum = 0.f;
    #pragma unroll
    for (int ni = 0; ni < 12; ++ni) {
      float p = __expf((sa[ni][r] - mx) * 0.125f);
      sum += p;
      int col = ni * 16 + (lane & 15);
      int pb = (prow * 384 + col * 2) ^ ((prow & 7) << 4);
      *(unsigned short*)((char*)Pw + pb) = f2bf(p);
    }
    sum += __shfl_xor(sum, 1, 64);
    sum += __shfl_xor(sum, 2, 64);
    sum += __shfl_xor(sum, 4, 64);
    sum += __shfl_xor(sum, 8, 64);
    l4[r] = sum;
  }

  f32x4 oa[4];
  #pragma unroll
  for (int ni = 0; ni < 4; ++ni) oa[ni] = (f32x4){0.f, 0.f, 0.f, 0.f};
  #pragma unroll
  for (int ks = 0; ks < 6; ++ks) {
    int kk = (ks << 5) + ((lane >> 4) << 3);
    int m = lane & 15;
    int pb = (m * 384 + kk * 2) ^ ((m & 7) << 4);
    short8v pa = *(const short8v*)((char*)Pw + pb);
    #pragma unroll
    for (int ni = 0; ni < 4; ++ni) {
      int vrow = ni * 16 + (lane & 15);
      int vb = (vrow * 384 + kk * 2) ^ ((vrow & 7) << 4);
      short8v vbf = *(const short8v*)((char*)Vt + vb);
      oa[ni] = __builtin_amdgcn_mfma_f32_16x16x32_bf16(pa, vbf, oa[ni], 0, 0, 0);
    }
  }

  int rbq = (lane >> 4) << 2;
  #pragma unroll
  for (int r = 0; r < 4; ++r) {
    float inv = 1.f / l4[r];
    unsigned short* dst = o + (size_t)(n * SEQ + q0 + rbq + r) * 512 + h * 64 + (lane & 15);
    #pragma unroll
    for (int ni = 0; ni < 4; ++ni)
      dst[ni * 16] = f2bf(oa[ni][r] * inv);
  }
}

// ---------------------------------------------------------------------------
extern "C" void kernel_launch(void* const* d_in, const int* in_sizes, int n_in,
                              void* d_out, int out_size, void* d_ws, size_t ws_size,
                              hipStream_t stream) {
  const float* img   = (const float*)d_in[0];
  const float* ln1_g = (const float*)d_in[1];
  const float* ln1_b = (const float*)d_in[2];
  const float* wqkv  = (const float*)d_in[3];
  const float* wo    = (const float*)d_in[4];
  const float* bo    = (const float*)d_in[5];
  const float* ln2_g = (const float*)d_in[6];
  const float* ln2_b = (const float*)d_in[7];
  const float* w1    = (const float*)d_in[8];
  const float* b1    = (const float*)d_in[9];
  const float* w2    = (const float*)d_in[10];
  const float* b2    = (const float*)d_in[11];
  float* out = (float*)d_out;

  char* ws = (char*)d_ws;
  unsigned short* x    = (unsigned short*)ws;               //  6,291,456 (bf16)
  unsigned short* big  = (unsigned short*)(ws + 6291456);   // 12,582,912
  unsigned short* ob   = (unsigned short*)(ws + 18874368);  //  3,145,728
  float2*         psum = (float2*)(ws + 22020096);          //    786,432
  float2*         cvq  = (float2*)(ws + 22806528);          //     12,288
  float2*         cvw  = (float2*)(ws + 22818816);          //     16,384
  float2*         pcv  = (float2*)(ws + 22835200);          //    524,288
  unsigned short* wtb  = (unsigned short*)(ws + 23359488);  // 12,582,912
  // total 35,942,400 B

  size_t per_qkv = (size_t)1024 * 1536, per_o = (size_t)512 * 1024;
  size_t per_1   = (size_t)1024 * 2048, per_2 = (size_t)2048 * 1024;
  unsigned short* wt_qkv = wtb;
  unsigned short* wt_o   = wt_qkv + per_qkv;
  unsigned short* wt_1   = wt_o + per_o;
  unsigned short* wt_2   = wt_1 + per_1;

  preproc_k<<<dim3(32, 16), 256, 0, stream>>>(img, x, psum);

  for (int l = 0; l < 6; ++l) {
    // qkv weights: fold ln1_g, emit column partials, reduce -> cvq
    wconv_k<<<dim3(1536 / 32, 1024 / 32), 256, 0, stream>>>(
        wqkv + l * per_qkv, ln1_g + l * 1024, ln1_b + l * 1024, wt_qkv, pcv, 1024, 1536);
    cvred_k<<<1536 / 256, 256, 0, stream>>>(pcv, nullptr, cvq, 32, 1536);
    wconv_k<<<dim3(1024 / 32,  512 / 32), 256, 0, stream>>>(
        wo + l * per_o, nullptr, nullptr, wt_o, nullptr, 512, 1024);
    // w1 weights: fold ln2_g, partials, reduce (+b1) -> cvw
    wconv_k<<<dim3(2048 / 32, 1024 / 32), 256, 0, stream>>>(
        w1 + l * per_1, ln2_g + l * 1024, ln2_b + l * 1024, wt_1, pcv, 1024, 2048);
    cvred_k<<<2048 / 256, 256, 0, stream>>>(pcv, b1 + l * 2048, cvw, 32, 2048);
    wconv_k<<<dim3(1024 / 32, 2048 / 32), 256, 0, stream>>>(
        w2 + l * per_2, nullptr, nullptr, wt_2, nullptr, 2048, 1024);

    // qkv: LN1-folded consumer
    mm_k<0><<<dim3(1536 / 64, 24), 256, 0, stream>>>(
        x, wt_qkv, nullptr, nullptr, cvq, psum, nullptr, big, MROWS, 1536, 1024);
    attn_k<<<dim3(3, 8, 16), 256, 0, stream>>>(big, ob);
    // wo: residual writer + LN2 stats producer
    mm_k<1><<<dim3(1024 / 64, 24), 256, 0, stream>>>(
        ob, wt_o, bo + l * 1024, x, nullptr, nullptr, psum, x, MROWS, 1024, 512);
    // w1: LN2-folded consumer + GELU
    mm_k<2><<<dim3(2048 / 64, 24), 256, 0, stream>>>(
        x, wt_1, nullptr, nullptr, cvw, psum, nullptr, big, MROWS, 2048, 1024);
    // w2: residual writer + next-layer LN1 stats producer
    mm_k<1><<<dim3(1024 / 64, 24), 256, 0, stream>>>(
        big, wt_2, b2 + l * 1024, x, nullptr, nullptr, psum, x, MROWS, 1024, 2048);
  }

  postproc_k<<<dim3(32, 16), 256, 0, stream>>>(x, out);
}

// Round 13
// 671.437 us; speedup vs baseline: 1.6862x; 1.1972x over previous
//
#include <hip/hip_runtime.h>
#include <math.h>

// ---------------------------------------------------------------------------
// JPEG-domain ViT. Round 13: LN-fold v2.
//  - No helper reductions: consumer GEMM prologue computes rowstats (128 rows)
//    AND column constants (64 cols, from wconv's chunk partials) itself, with
//    fully unrolled independent loads; strictly before STAGE (vmcnt-safe).
//  - All 4 weight conversions merged into ONE 6144-block dispatch per layer.
//  - 38 dispatches total (was 68). mm_k K-loop = proven round-8 structure.
// ---------------------------------------------------------------------------

#define NIMG 16
#define SEQ 192
#define DIMV 1024
#define MROWS (NIMG * SEQ)   // 3072

typedef __attribute__((ext_vector_type(8))) short short8v;
typedef __attribute__((ext_vector_type(4))) float f32x4;
typedef unsigned int uint_t;

__device__ __forceinline__ unsigned short f2bf(float f) {
  union { float f; uint_t u; } x; x.f = f;
  uint_t r = x.u + 0x7fffu + ((x.u >> 16) & 1u);
  return (unsigned short)(r >> 16);
}
__device__ __forceinline__ float bf2f(unsigned short h) {
  union { uint_t u; float f; } y; y.u = ((uint_t)h) << 16;
  return y.f;
}

__device__ __forceinline__ void gload16(const void* g, void* l) {
  __builtin_amdgcn_global_load_lds(
      reinterpret_cast<const __attribute__((address_space(1))) void*>(
          reinterpret_cast<uintptr_t>(g)),
      reinterpret_cast<__attribute__((address_space(3))) void*>(
          reinterpret_cast<uintptr_t>(l)),
      16, 0, 0);
}

__constant__ float DCT8c[8][8] = {
  { 0.35355339f, 0.35355339f, 0.35355339f, 0.35355339f, 0.35355339f, 0.35355339f, 0.35355339f, 0.35355339f},
  { 0.49039264f, 0.41573481f, 0.27778512f, 0.09754516f,-0.09754516f,-0.27778512f,-0.41573481f,-0.49039264f},
  { 0.46193977f, 0.19134172f,-0.19134172f,-0.46193977f,-0.46193977f,-0.19134172f, 0.19134172f, 0.46193977f},
  { 0.41573481f,-0.09754516f,-0.49039264f,-0.27778512f, 0.27778512f, 0.49039264f, 0.09754516f,-0.41573481f},
  { 0.35355339f,-0.35355339f,-0.35355339f, 0.35355339f, 0.35355339f,-0.35355339f,-0.35355339f, 0.35355339f},
  { 0.27778512f,-0.49039264f, 0.09754516f, 0.41573481f,-0.41573481f,-0.09754516f, 0.49039264f,-0.27778512f},
  { 0.19134172f,-0.46193977f, 0.46193977f,-0.19134172f,-0.19134172f, 0.46193977f,-0.46193977f, 0.19134172f},
  { 0.09754516f,-0.27778512f, 0.41573481f,-0.49039264f, 0.49039264f,-0.41573481f, 0.27778512f,-0.09754516f}
};

// ---------------- preprocess: block = (hb, n); writes x bf16 + row partials -
__global__ __launch_bounds__(256) void preproc_k(const float* __restrict__ img,
                                                 unsigned short* __restrict__ x0,
                                                 float2* __restrict__ psum) {
  int hb = blockIdx.x, n = blockIdx.y;
  __shared__ float yuv[3][8][256];
  __shared__ float tmpA[8][264];
  __shared__ float coefc[64][33];
  int t = threadIdx.x;

  #pragma unroll
  for (int u = 0; u < 8; ++u) {
    int idx = u * 256 + t;
    int i = idx >> 8, xx = idx & 255;
    size_t pix = ((size_t)(n * 3) * 256 + hb * 8 + i) * 256 + xx;
    float r = img[pix], g = img[pix + 65536], b = img[pix + 131072];
    yuv[0][i][xx] =  0.299f   * r + 0.587f   * g + 0.114f   * b;
    yuv[1][i][xx] = -0.14713f * r - 0.28886f * g + 0.436f   * b;
    yuv[2][i][xx] =  0.615f   * r - 0.51499f * g - 0.10001f * b;
  }

  for (int c = 0; c < 3; ++c) {
    __syncthreads();
    #pragma unroll
    for (int u = 0; u < 8; ++u) {
      int idx = u * 256 + t;
      int p = idx >> 8, xx = idx & 255;
      float a = 0.f;
      #pragma unroll
      for (int k = 0; k < 8; ++k) a += DCT8c[p][k] * yuv[c][k][xx];
      tmpA[p][xx] = a;
    }
    __syncthreads();
    #pragma unroll
    for (int u = 0; u < 8; ++u) {
      int idx = u * 256 + t;
      int wb = idx >> 6, s = idx & 63;
      int p = s >> 3, qq = s & 7;
      float a = 0.f;
      #pragma unroll
      for (int j = 0; j < 8; ++j) a += tmpA[p][wb * 8 + j] * DCT8c[qq][j];
      bool keep = (c == 0) ? ((p + qq) <= 5 || ((p + qq) == 6 && qq < 4))
                           : ((p + qq) <= 2 || ((p + qq) == 3 && p < 3));
      coefc[s][wb] = keep ? a : 0.f;
    }
    __syncthreads();
    #pragma unroll
    for (int u = 0; u < 8; ++u) {
      int idx = u * 256 + t;
      int s = idx >> 5, wb = idx & 31;
      x0[((size_t)(n * SEQ) + c * 64 + s) * DIMV + hb * 32 + wb] = f2bf(coefc[s][wb]);
    }
    if (t < 64) {
      float sm = 0.f, sq = 0.f;
      #pragma unroll
      for (int wb = 0; wb < 32; ++wb) {
        float v = bf2f(f2bf(coefc[t][wb]));
        sm += v; sq += v * v;
      }
      psum[(((size_t)(n * SEQ) + c * 64 + t) << 5) + hb] = make_float2(sm, sq);
    }
  }
}

// ---------------- postprocess (coalesced): block = (hb, n), x bf16 ---------
__global__ __launch_bounds__(256) void postproc_k(const unsigned short* __restrict__ x,
                                                  float* __restrict__ out) {
  int hb = blockIdx.x, n = blockIdx.y;
  __shared__ float coefc[64][33];
  __shared__ float tmpA[8][264];
  __shared__ float rec[3][8][256];
  int t = threadIdx.x;

  for (int c = 0; c < 3; ++c) {
    __syncthreads();
    #pragma unroll
    for (int u = 0; u < 8; ++u) {
      int idx = u * 256 + t;
      int s = idx >> 5, wb = idx & 31;
      coefc[s][wb] = bf2f(x[((size_t)(n * SEQ) + c * 64 + s) * DIMV + hb * 32 + wb]);
    }
    __syncthreads();
    #pragma unroll
    for (int u = 0; u < 8; ++u) {
      int idx = u * 256 + t;
      int wb = idx >> 6, iq = idx & 63;
      int i = iq >> 3, qq = iq & 7;
      float a = 0.f;
      #pragma unroll
      for (int p = 0; p < 8; ++p) a += DCT8c[i][p] * coefc[p * 8 + qq][wb];
      tmpA[i][wb * 8 + qq] = a;
    }
    __syncthreads();
    #pragma unroll
    for (int u = 0; u < 8; ++u) {
      int idx = u * 256 + t;
      int i = idx >> 8, xx = idx & 255;
      int wb = xx >> 3, j = xx & 7;
      float a = 0.f;
      #pragma unroll
      for (int qq = 0; qq < 8; ++qq) a += tmpA[i][wb * 8 + qq] * DCT8c[j][qq];
      rec[c][i][xx] = a;
    }
  }
  __syncthreads();
  #pragma unroll
  for (int u = 0; u < 8; ++u) {
    int idx = u * 256 + t;
    int i = idx >> 8, xx = idx & 255;
    float y = rec[0][i][xx], uu = rec[1][i][xx], v = rec[2][i][xx];
    size_t pix = ((size_t)(n * 3) * 256 + hb * 8 + i) * 256 + xx;
    out[pix]          = y + 1.13983f * v;
    out[pix + 65536]  = y - 0.39465f * uu - 0.5806f * v;
    out[pix + 131072] = y + 2.03211f * uu;
  }
}

// ---------------- merged weight prep: all 4 weights of one layer ------------
// Flat 1-D grid of 6144 blocks:
//   [0,1536):    wqkv  K=1024 N=1536  fold ln1_g, partials -> pcv_q
//   [1536,2048): wo    K=512  N=1024
//   [2048,4096): w1    K=1024 N=2048  fold ln2_g, partials -> pcv_w
//   [4096,6144): w2    K=2048 N=1024
// Each block: 32x32 fp32 tile -> LDS -> bf16 transpose [N][K]; folded tiles
// also emit per-32-row-chunk column partials (c1=sum g*W, c2=sum b*W).
__global__ __launch_bounds__(256) void wconv_all(
    const float* __restrict__ wqkv, const float* __restrict__ wo,
    const float* __restrict__ w1,   const float* __restrict__ w2,
    const float* __restrict__ ln1_g, const float* __restrict__ ln1_b,
    const float* __restrict__ ln2_g, const float* __restrict__ ln2_b,
    unsigned short* __restrict__ wt_qkv, unsigned short* __restrict__ wt_o,
    unsigned short* __restrict__ wt_1,   unsigned short* __restrict__ wt_2,
    float2* __restrict__ pcv_q, float2* __restrict__ pcv_w) {
  int bid = blockIdx.x;
  const float *w, *g = nullptr, *b = nullptr;
  unsigned short* wt;
  float2* pcv = nullptr;
  int K, N, bx, by;
  if (bid < 1536) {
    int r = bid;        w = wqkv; g = ln1_g; b = ln1_b; wt = wt_qkv; pcv = pcv_q;
    K = 1024; N = 1536; bx = r % 48; by = r / 48;
  } else if (bid < 2048) {
    int r = bid - 1536; w = wo;   wt = wt_o;
    K = 512;  N = 1024; bx = r % 32; by = r / 32;
  } else if (bid < 4096) {
    int r = bid - 2048; w = w1;   g = ln2_g; b = ln2_b; wt = wt_1; pcv = pcv_w;
    K = 1024; N = 2048; bx = r % 64; by = r / 64;
  } else {
    int r = bid - 4096; w = w2;   wt = wt_2;
    K = 2048; N = 1024; bx = r % 32; by = r / 32;
  }
  __shared__ float s[32][33];
  int t = threadIdx.x;
  int n0 = bx << 5, k0 = by << 5;
  int r = t >> 3, c4 = (t & 7) << 2;
  float4 v = *(const float4*)(w + (size_t)(k0 + r) * N + n0 + c4);
  s[r][c4] = v.x; s[r][c4 + 1] = v.y; s[r][c4 + 2] = v.z; s[r][c4 + 3] = v.w;
  __syncthreads();
  float g0 = 1.f, g1 = 1.f, g2 = 1.f, g3 = 1.f;
  if (g) {
    g0 = g[k0 + c4]; g1 = g[k0 + c4 + 1]; g2 = g[k0 + c4 + 2]; g3 = g[k0 + c4 + 3];
  }
  ushort4 o;
  o.x = f2bf(s[c4 + 0][r] * g0); o.y = f2bf(s[c4 + 1][r] * g1);
  o.z = f2bf(s[c4 + 2][r] * g2); o.w = f2bf(s[c4 + 3][r] * g3);
  *(ushort4*)(wt + (size_t)(n0 + r) * K + k0 + c4) = o;
  if (pcv && t < 32) {
    float c1 = 0.f, c2 = 0.f;
    #pragma unroll
    for (int rr = 0; rr < 32; ++rr) {
      float wv = s[rr][t];
      c1 += g[k0 + rr] * wv;
      c2 += b[k0 + rr] * wv;
    }
    pcv[(size_t)(k0 >> 5) * N + n0 + t] = make_float2(c1, c2);
  }
}

// ---------------- bf16 MFMA GEMM: 128x64 tile, 4 waves, BK=64 (round 8) -----
//  EPI 0 (qkv): LN-consumer. Prologue: rowstats from psum (t<128) +
//               colstats from pcv chunk partials (t in [128,192)).
//               v = rs*acc - mu*rs*c1[col] + c2[col] -> bf16.
//  EPI 1 (wo/w2): +bias +bf16 residual -> bf16; per-row (sum,sumsq) partial
//                 for its 32-col chunk -> psum_out (LN stats producer).
//  EPI 2 (w1): LN-consumer + exact GELU; colstats add bias (=b1).
// Prologue loads complete (and drain via __syncthreads) BEFORE STAGE, so the
// counted vmcnt(6) pipeline is unaffected.
template <int EPI>
__global__ __launch_bounds__(256) void mm_k(const unsigned short* __restrict__ A,
                                            const unsigned short* __restrict__ Bt,
                                            const float* __restrict__ bias,
                                            const unsigned short* res,
                                            const float2* __restrict__ pcv,
                                            const float2* __restrict__ psum_in,
                                            float2* __restrict__ psum_out,
                                            unsigned short* Cout,
                                            int M, int N, int K) {
  __shared__ __align__(16) unsigned short smem[24576];   // 48 KB staging
  __shared__ float rowstats[128][2];                      // mu*rs, rs
  __shared__ float2 colstats[64];                         // c1, c2

  int t = threadIdx.x;
  int lane = t & 63, w = t >> 6;          // 4 waves
  int gx = gridDim.x;
  int nwg = gx * gridDim.y;
  int bid = blockIdx.y * gx + blockIdx.x;
  bid = (bid & 7) * (nwg >> 3) + (bid >> 3);      // bijective XCD swizzle
  int m0 = (bid / gx) << 7, n0 = (bid % gx) << 6;
  int wm = (w >> 1) << 6, wn = (w & 1) << 5;

  if (EPI != 1) {
    if (t < 128) {
      const float2* pr = psum_in + ((size_t)(m0 + t) << 5);
      float sm = 0.f, sq = 0.f;
      #pragma unroll
      for (int i2 = 0; i2 < 32; ++i2) { float2 pv = pr[i2]; sm += pv.x; sq += pv.y; }
      float inv = 1.f / (float)K;
      float mu = sm * inv;
      float var = fmaxf(sq * inv - mu * mu, 0.f);
      float rsv = rsqrtf(var + 1e-5f);
      rowstats[t][0] = mu * rsv;
      rowstats[t][1] = rsv;
    } else if (t < 192) {
      int col = n0 + (t - 128);
      float c1 = 0.f, c2 = 0.f;
      #pragma unroll
      for (int c = 0; c < 32; ++c) {   // K==1024 for all LN-consumers
        float2 pch = pcv[(size_t)c * N + col];
        c1 += pch.x; c2 += pch.y;
      }
      if (EPI == 2) c2 += bias[col];
      colstats[t - 128] = make_float2(c1, c2);
    }
    __syncthreads();   // drains prologue loads; vmcnt back to 0 before STAGE
  }

  int r_in = lane >> 3, p = lane & 7;
  int sw = (p ^ r_in) << 3;
  const unsigned short* Ag = A + (size_t)(m0 + w * 32 + r_in) * K + sw;
  const unsigned short* Bg = Bt + (size_t)(n0 + w * 16 + r_in) * K + sw;
  char* smb = (char*)smem;
  size_t K8 = (size_t)K * 8;

  f32x4 acc[4][2] = {};

  int m15 = lane & 15, c4 = lane >> 4, s7 = lane & 7;
  int nt = K >> 6;

  #define STAGE(it_, db_) {                                                    \
    size_t k0_ = (size_t)(it_) << 6;                                           \
    gload16(Ag + k0_,          smb + (db_) * 16384 + ((w * 32 +  0) << 7));    \
    gload16(Ag + k0_ + K8,     smb + (db_) * 16384 + ((w * 32 +  8) << 7));    \
    gload16(Ag + k0_ + 2 * K8, smb + (db_) * 16384 + ((w * 32 + 16) << 7));    \
    gload16(Ag + k0_ + 3 * K8, smb + (db_) * 16384 + ((w * 32 + 24) << 7));    \
    gload16(Bg + k0_,          smb + 32768 + (db_) * 8192 + ((w * 16 + 0) << 7)); \
    gload16(Bg + k0_ + K8,     smb + 32768 + (db_) * 8192 + ((w * 16 + 8) << 7)); }

  STAGE(0, 0);
  STAGE(1, 1);

  for (int it = 0; it < nt; ++it) {
    int db = it & 1;
    if (it + 1 < nt) asm volatile("s_waitcnt vmcnt(6)" ::: "memory");
    else             asm volatile("s_waitcnt vmcnt(0)" ::: "memory");
    __builtin_amdgcn_s_barrier();
    const char* Ab = smb + db * 16384;
    const char* Bb = smb + 32768 + db * 8192;
    short8v a[2][4], b[2][2];
    #pragma unroll
    for (int kc = 0; kc < 2; ++kc) {
      int ch = ((kc << 2) + c4);
      #pragma unroll
      for (int mi = 0; mi < 4; ++mi)
        a[kc][mi] = *(const short8v*)(Ab + ((wm + mi * 16 + m15) << 7) + ((ch ^ s7) << 4));
      #pragma unroll
      for (int ni = 0; ni < 2; ++ni)
        b[kc][ni] = *(const short8v*)(Bb + ((wn + ni * 16 + m15) << 7) + ((ch ^ s7) << 4));
    }
    #pragma unroll
    for (int kc = 0; kc < 2; ++kc)
      #pragma unroll
      for (int mi = 0; mi < 4; ++mi)
        #pragma unroll
        for (int ni = 0; ni < 2; ++ni)
          acc[mi][ni] = __builtin_amdgcn_mfma_f32_16x16x32_bf16(a[kc][mi], b[kc][ni], acc[mi][ni], 0, 0, 0);
    __builtin_amdgcn_s_barrier();
    if (it + 2 < nt) STAGE(it + 2, db);
  }
  #undef STAGE

  // epilogue: C/D frag layout col = lane&15, row = (lane>>4)*4 + r  [m89/m91]
  int cn = lane & 15;
  int rbq = (lane >> 4) << 2;
  #pragma unroll
  for (int mi = 0; mi < 4; ++mi) {
    float vq[2][4];
    #pragma unroll
    for (int ni = 0; ni < 2; ++ni) {
      int col = n0 + wn + ni * 16 + cn;
      float2 cv = make_float2(0.f, 0.f);
      float bv = 0.f;
      if (EPI != 1) cv = colstats[wn + ni * 16 + cn];
      else          bv = bias[col];
      #pragma unroll
      for (int r = 0; r < 4; ++r) {
        int row = m0 + wm + mi * 16 + rbq + r;
        float v = acc[mi][ni][r];
        if (EPI == 1) {
          v += bv + bf2f(res[(size_t)row * N + col]);
          unsigned short hv = f2bf(v);
          Cout[(size_t)row * N + col] = hv;
          vq[ni][r] = bf2f(hv);
        } else {
          int lr = wm + mi * 16 + rbq + r;
          float v2 = rowstats[lr][1] * v - rowstats[lr][0] * cv.x + cv.y;
          if (EPI == 2) v2 = 0.5f * v2 * (1.f + erff(v2 * 0.70710678f));
          Cout[(size_t)row * N + col] = f2bf(v2);
        }
      }
    }
    if (EPI == 1) {
      #pragma unroll
      for (int r = 0; r < 4; ++r) {
        float sm = vq[0][r] + vq[1][r];
        float sq = vq[0][r] * vq[0][r] + vq[1][r] * vq[1][r];
        #pragma unroll
        for (int msk = 1; msk <= 8; msk <<= 1) {
          sm += __shfl_xor(sm, msk, 64);
          sq += __shfl_xor(sq, msk, 64);
        }
        if ((lane & 15) == 0) {
          int row = m0 + wm + mi * 16 + rbq + r;
          psum_out[((size_t)row << 5) + ((n0 + wn) >> 5)] = make_float2(sm, sq);
        }
      }
    }
  }
}

// ---------------- MFMA attention (round 3, unchanged) -----------------------
__global__ __launch_bounds__(256) void attn_k(const unsigned short* __restrict__ qkv,
                                              unsigned short* __restrict__ o) {
  int qt = blockIdx.x, h = blockIdx.y, n = blockIdx.z;
  int t = threadIdx.x, lane = t & 63, w = t >> 6;
  __shared__ __align__(16) unsigned short Ks[192 * 64];
  __shared__ __align__(16) unsigned short Vt[64 * 192];
  __shared__ __align__(16) unsigned short Ps[4][16 * 192];
  const unsigned short* base = qkv + (size_t)n * SEQ * 1536;

  #pragma unroll
  for (int i = 0; i < 6; ++i) {
    int idx = i * 256 + t;
    int row = idx >> 3, c8 = (idx & 7) << 3;
    short8v kv = *(const short8v*)(base + (size_t)row * 1536 + 512 + h * 64 + c8);
    int kb = (row * 128 + c8 * 2) ^ ((row & 7) << 4);
    *(short8v*)((char*)Ks + kb) = kv;
  }
  #pragma unroll
  for (int i = 0; i < 6; ++i) {
    int idx = i * 256 + t;
    int j = (idx & 63) + ((idx >> 9) << 6);
    int d0 = ((idx >> 6) & 7) << 3;
    short8v vv = *(const short8v*)(base + (size_t)j * 1536 + 1024 + h * 64 + d0);
    #pragma unroll
    for (int e = 0; e < 8; ++e) {
      int d = d0 + e;
      int vb = (d * 384 + j * 2) ^ ((d & 7) << 4);
      *(unsigned short*)((char*)Vt + vb) = (unsigned short)vv[e];
    }
  }
  int q0 = qt * 64 + w * 16;
  const unsigned short* qp = base + (size_t)(q0 + (lane & 15)) * 1536 + h * 64 + ((lane >> 4) << 3);
  short8v aq0 = *(const short8v*)(qp);
  short8v aq1 = *(const short8v*)(qp + 32);
  __syncthreads();

  f32x4 sa[12];
  #pragma unroll
  for (int ni = 0; ni < 12; ++ni) sa[ni] = (f32x4){0.f, 0.f, 0.f, 0.f};
  #pragma unroll
  for (int ks = 0; ks < 2; ++ks) {
    int kk = (ks << 5) + ((lane >> 4) << 3);
    short8v aq = ks ? aq1 : aq0;
    #pragma unroll
    for (int ni = 0; ni < 12; ++ni) {
      int krow = ni * 16 + (lane & 15);
      int kb = (krow * 128 + kk * 2) ^ ((krow & 7) << 4);
      short8v bk = *(const short8v*)((char*)Ks + kb);
      sa[ni] = __builtin_amdgcn_mfma_f32_16x16x32_bf16(aq, bk, sa[ni], 0, 0, 0);
    }
  }

  unsigned short* Pw = Ps[w];
  float l4[4];
  #pragma unroll
  for (int r = 0; r < 4; ++r) {
    float mx = sa[0][r];
    #pragma unroll
    for (int ni = 1; ni < 12; ++ni) mx = fmaxf(mx, sa[ni][r]);
    mx = fmaxf(mx, __shfl_xor(mx, 1, 64));
    mx = fmaxf(mx, __shfl_xor(mx, 2, 64));
    mx = fmaxf(mx, __shfl_xor(mx, 4, 64));
    mx = fmaxf(mx, __shfl_xor(mx, 8, 64));
    int prow = ((lane >> 4) << 2) + r;
    float sum = 0.f;
    #pragma unroll
    for (int ni = 0; ni < 12; ++ni) {
      float p = __expf((sa[ni][r] - mx) * 0.125f);
      sum += p;
      int col = ni * 16 + (lane & 15);
      int pb = (prow * 384 + col * 2) ^ ((prow & 7) << 4);
      *(unsigned short*)((char*)Pw + pb) = f2bf(p);
    }
    sum += __shfl_xor(sum, 1, 64);
    sum += __shfl_xor(sum, 2, 64);
    sum += __shfl_xor(sum, 4, 64);
    sum += __shfl_xor(sum, 8, 64);
    l4[r] = sum;
  }

  f32x4 oa[4];
  #pragma unroll
  for (int ni = 0; ni < 4; ++ni) oa[ni] = (f32x4){0.f, 0.f, 0.f, 0.f};
  #pragma unroll
  for (int ks = 0; ks < 6; ++ks) {
    int kk = (ks << 5) + ((lane >> 4) << 3);
    int m = lane & 15;
    int pb = (m * 384 + kk * 2) ^ ((m & 7) << 4);
    short8v pa = *(const short8v*)((char*)Pw + pb);
    #pragma unroll
    for (int ni = 0; ni < 4; ++ni) {
      int vrow = ni * 16 + (lane & 15);
      int vb = (vrow * 384 + kk * 2) ^ ((vrow & 7) << 4);
      short8v vbf = *(const short8v*)((char*)Vt + vb);
      oa[ni] = __builtin_amdgcn_mfma_f32_16x16x32_bf16(pa, vbf, oa[ni], 0, 0, 0);
    }
  }

  int rbq = (lane >> 4) << 2;
  #pragma unroll
  for (int r = 0; r < 4; ++r) {
    float inv = 1.f / l4[r];
    unsigned short* dst = o + (size_t)(n * SEQ + q0 + rbq + r) * 512 + h * 64 + (lane & 15);
    #pragma unroll
    for (int ni = 0; ni < 4; ++ni)
      dst[ni * 16] = f2bf(oa[ni][r] * inv);
  }
}

// ---------------------------------------------------------------------------
extern "C" void kernel_launch(void* const* d_in, const int* in_sizes, int n_in,
                              void* d_out, int out_size, void* d_ws, size_t ws_size,
                              hipStream_t stream) {
  const float* img   = (const float*)d_in[0];
  const float* ln1_g = (const float*)d_in[1];
  const float* ln1_b = (const float*)d_in[2];
  const float* wqkv  = (const float*)d_in[3];
  const float* wo    = (const float*)d_in[4];
  const float* bo    = (const float*)d_in[5];
  const float* ln2_g = (const float*)d_in[6];
  const float* ln2_b = (const float*)d_in[7];
  const float* w1    = (const float*)d_in[8];
  const float* b1    = (const float*)d_in[9];
  const float* w2    = (const float*)d_in[10];
  const float* b2    = (const float*)d_in[11];
  float* out = (float*)d_out;

  char* ws = (char*)d_ws;
  unsigned short* x     = (unsigned short*)ws;               //  6,291,456 (bf16)
  unsigned short* big   = (unsigned short*)(ws + 6291456);   // 12,582,912
  unsigned short* ob    = (unsigned short*)(ws + 18874368);  //  3,145,728
  float2*         psum  = (float2*)(ws + 22020096);          //    786,432
  float2*         pcv_q = (float2*)(ws + 22806528);          //    393,216
  float2*         pcv_w = (float2*)(ws + 23199744);          //    524,288
  unsigned short* wtb   = (unsigned short*)(ws + 23724032);  // 12,582,912
  // total 36,306,944 B (< 47.2 MB proven available)

  size_t per_qkv = (size_t)1024 * 1536, per_o = (size_t)512 * 1024;
  size_t per_1   = (size_t)1024 * 2048, per_2 = (size_t)2048 * 1024;
  unsigned short* wt_qkv = wtb;
  unsigned short* wt_o   = wt_qkv + per_qkv;
  unsigned short* wt_1   = wt_o + per_o;
  unsigned short* wt_2   = wt_1 + per_1;

  preproc_k<<<dim3(32, 16), 256, 0, stream>>>(img, x, psum);

  for (int l = 0; l < 6; ++l) {
    wconv_all<<<6144, 256, 0, stream>>>(
        wqkv + l * per_qkv, wo + l * per_o, w1 + l * per_1, w2 + l * per_2,
        ln1_g + l * 1024, ln1_b + l * 1024, ln2_g + l * 1024, ln2_b + l * 1024,
        wt_qkv, wt_o, wt_1, wt_2, pcv_q, pcv_w);

    // qkv: LN1-folded consumer
    mm_k<0><<<dim3(1536 / 64, 24), 256, 0, stream>>>(
        x, wt_qkv, nullptr, nullptr, pcv_q, psum, nullptr, big, MROWS, 1536, 1024);
    attn_k<<<dim3(3, 8, 16), 256, 0, stream>>>(big, ob);
    // wo: residual writer + LN2 stats producer
    mm_k<1><<<dim3(1024 / 64, 24), 256, 0, stream>>>(
        ob, wt_o, bo + l * 1024, x, nullptr, nullptr, psum, x, MROWS, 1024, 512);
    // w1: LN2-folded consumer + GELU (b1 added to colstats in prologue)
    mm_k<2><<<dim3(2048 / 64, 24), 256, 0, stream>>>(
        x, wt_1, b1 + l * 2048, nullptr, pcv_w, psum, nullptr, big, MROWS, 2048, 1024);
    // w2: residual writer + next-layer LN1 stats producer
    mm_k<1><<<dim3(1024 / 64, 24), 256, 0, stream>>>(
        big, wt_2, b2 + l * 1024, x, nullptr, nullptr, psum, x, MROWS, 1024, 2048);
  }

  postproc_k<<<dim3(32, 16), 256, 0, stream>>>(x, out);
}